// Round 13
// baseline (5769.142 us; speedup 1.0000x reference)
//
#include <hip/hip_runtime.h>
#include <hip/hip_bf16.h>

// NeuralODE RK4, bf16 MFMA persistent kernel, swapped-operand layout,
// DUAL-TILE 16-WAVE WG (occupancy 4 waves/SIMD).
// BS=1024, ZDIM=HID=256, TLEN=128 -> 127 steps x 4 stages = 508 f-evals.
//
// Measured landscape (R1-R12): the proven per-tile schedule is R5's
// 8 waves x 16 rows (503us): hsh table, pre-rotated slices, deferred kacc.
// All variations below 8 waves lost >=30% (latency exposure); peel (R12)
// and spin-dataflow (R10) lost to fence/flag overhead. Untested axis:
// occupancy ABOVE 2 waves/SIMD. The LDS fabric is rated 256B/cyc/CU
// (~512 cyc for a stage's 128KB) but we observe ~1536cy — the pipe idles
// during each wave's tanh/pack tails, ramps and barrier drains.
//
// This revision: ONE 1024-thread WG = 16 waves = 4/SIMD, owning TWO
// independent 16-row tiles. Waves 0-7 run tile A, waves 8-15 tile B, each
// group exactly the R5 schedule on its own zbuf/hbuf. WG-wide barriers are
// compatible (both groups execute 2/stage); within barrier intervals waves
// drift, so group A's VALU tails overlap group B's LDS reads -> higher LDS
// pipe utilization per CU. 120 VGPR/wave x 4 waves/SIMD: no spill.
//
// Swapped trick: S^T = W^T @ z^T (weights as MFMA A-operand). C/D layout:
// col(lane&15) = batch row m, row(q*4+r) = output col c. LDS round-trip is
// per-m contiguous: packed b64 writes, b128 frag reads, row stride 264 u16.
// Rotated k-slice order ks=(wvl+i)&7, weights PRE-ROTATED at load (static
// register indices; R4: runtime idx -> scratch, 6.6x).

#define BS   1024
#define ZDIM 256
#define TLEN 128
#define ROWSTRIDE 264   // u16 units; 528 B = 16B-aligned, odd multiple of 4 units

typedef short v8s __attribute__((ext_vector_type(8)));
typedef float v4f __attribute__((ext_vector_type(4)));

static __device__ __forceinline__ ushort f2bf_rne(float x) {
    union { float f; unsigned u; } v; v.f = x;
    unsigned r = v.u + 0x7FFFu + ((v.u >> 16) & 1u);
    return (ushort)(r >> 16);
}

static __device__ __forceinline__ unsigned pk2(float a, float b) {
    union { __hip_bfloat162 h; unsigned u; } cv;
    cv.h = __float22bfloat162_rn(make_float2(a, b));
    return cv.u;
}

static __device__ __forceinline__ float fast_tanh(float x) {
    // tanh(x) = 1 - 2/(exp2(2x*log2e)+1); v_exp + v_rcp, no slow libm div
    float e = __builtin_amdgcn_exp2f(2.88539008177793f * x);
    float r = __builtin_amdgcn_rcpf(e + 1.0f);
    return 1.0f - 2.0f * r;
}

__global__ __launch_bounds__(1024, 4)
void ode_mfma_kernel(const float* __restrict__ z0,
                     const float* __restrict__ t,
                     const float* __restrict__ W1,
                     const float* __restrict__ b1,
                     const float* __restrict__ W2,
                     const float* __restrict__ b2,
                     float* __restrict__ out)
{
    // per-group state buffers, swapped layout: buf[m][c] bf16
    __shared__ ushort zbuf[2][16 * ROWSTRIDE];
    __shared__ ushort hbuf[2][16 * ROWSTRIDE];
    __shared__ float  hsh[TLEN];            // per-step h = t[s+1]-t[s]

    const int tid  = threadIdx.x;
    const int wv   = tid >> 6;        // 0..15
    const int grp  = wv >> 3;         // 0: tile A (waves 0-7), 1: tile B
    const int wvl  = wv & 7;          // wave within group
    const int lane = tid & 63;
    const int q    = lane >> 4;       // 0..3
    const int ln   = lane & 15;       // = batch row m (within tile)
    const int rowbase = blockIdx.x * 32 + grp * 16;

    ushort* const zb = zbuf[grp];
    ushort* const hb = hbuf[grp];

    if (tid < TLEN - 1) hsh[tid] = t[tid + 1] - t[tid];

    // ---- one-time: weights -> registers, A-frag layout, PRE-ROTATED ----
    // wf[ct][i] holds k-slice ks=(wvl+i)&7: lane has W[k=32ks+8q+j][c=32wvl+16ct+ln]
    v8s w1f[2][8], w2f[2][8];
    #pragma unroll
    for (int ct = 0; ct < 2; ++ct) {
        const int c = wvl * 32 + ct * 16 + ln;
        #pragma unroll
        for (int i = 0; i < 8; ++i) {
            const int ks = (wvl + i) & 7;
            v8s a, b;
            #pragma unroll
            for (int j = 0; j < 8; ++j) {
                const int k = ks * 32 + q * 8 + j;
                a[j] = (short)f2bf_rne(W1[k * ZDIM + c]);
                b[j] = (short)f2bf_rne(W2[k * ZDIM + c]);
            }
            w1f[ct][i] = a;
            w2f[ct][i] = b;
        }
    }

    // biases in C'-layout: value row (c = 32wvl + 16ct + 4q + r)
    v4f b1f[2], b2f[2];
    #pragma unroll
    for (int ct = 0; ct < 2; ++ct)
        #pragma unroll
        for (int r = 0; r < 4; ++r) {
            b1f[ct][r] = b1[wvl * 32 + ct * 16 + q * 4 + r];
            b2f[ct][r] = b2[wvl * 32 + ct * 16 + q * 4 + r];
        }

    // LDS offsets (u16 units); rdaddr[i] carries the matching slice rotation
    const int rdbase = ln * ROWSTRIDE + q * 8;             // + 32*ks, b128 reads
    const int wrbase = ln * ROWSTRIDE + wvl * 32 + q * 4;  // + 16*ct,  b64 writes
    int rdaddr[8];
    #pragma unroll
    for (int i = 0; i < 8; ++i)
        rdaddr[i] = rdbase + ((wvl + i) & 7) * 32;

    // ---- initial state ----
    float zloc[2][4];   // z[m=ln][c = 32wvl+16ct+4q+r], fp32
    #pragma unroll
    for (int ct = 0; ct < 2; ++ct) {
        #pragma unroll
        for (int r = 0; r < 4; ++r)
            zloc[ct][r] = z0[(rowbase + ln) * ZDIM + wvl * 32 + ct * 16 + q * 4 + r];
        uint2 p; p.x = pk2(zloc[ct][0], zloc[ct][1]); p.y = pk2(zloc[ct][2], zloc[ct][3]);
        *(uint2*)&zb[wrbase + ct * 16] = p;
    }
    __syncthreads();

    float kacc[2][4];

    #pragma unroll 1
    for (int step = 0; step < TLEN - 1; ++step) {
        const float h = hsh[step];

        #pragma unroll
        for (int stage = 0; stage < 4; ++stage) {
            // ---- GEMM1: S^T = W1^T z^T + b1 (rotated slice order) ----
            v4f acc0 = b1f[0], acc1 = b1f[1];
            #pragma unroll
            for (int i = 0; i < 8; ++i) {
                const v8s zf = *(const v8s*)&zb[rdaddr[i]];
                acc0 = __builtin_amdgcn_mfma_f32_16x16x32_bf16(w1f[0][i], zf, acc0, 0, 0, 0);
                acc1 = __builtin_amdgcn_mfma_f32_16x16x32_bf16(w1f[1][i], zf, acc1, 0, 0, 0);
            }
            // tanh -> hbuf; write p0 before computing p1 (shorter tail)
            {
                uint2 p0;
                p0.x = pk2(fast_tanh(acc0[0]), fast_tanh(acc0[1]));
                p0.y = pk2(fast_tanh(acc0[2]), fast_tanh(acc0[3]));
                *(uint2*)&hb[wrbase] = p0;
                uint2 p1;
                p1.x = pk2(fast_tanh(acc1[0]), fast_tanh(acc1[1]));
                p1.y = pk2(fast_tanh(acc1[2]), fast_tanh(acc1[3]));
                *(uint2*)&hb[wrbase + 16] = p1;
            }
            __syncthreads();

            // ---- GEMM2: f^T = W2^T h^T + b2 (rotated slice order) ----
            v4f fv0 = b2f[0], fv1 = b2f[1];
            #pragma unroll
            for (int i = 0; i < 8; ++i) {
                const v8s hf = *(const v8s*)&hb[rdaddr[i]];
                fv0 = __builtin_amdgcn_mfma_f32_16x16x32_bf16(w2f[0][i], hf, fv0, 0, 0, 0);
                fv1 = __builtin_amdgcn_mfma_f32_16x16x32_bf16(w2f[1][i], hf, fv1, 0, 0, 0);
            }

            // ---- RK4 epilogue: only zn pack+write before the barrier ----
            if (stage < 3) {
                const float c = (stage == 2) ? h : 0.5f * h;
                #pragma unroll
                for (int ct = 0; ct < 2; ++ct) {
                    const v4f f = ct ? fv1 : fv0;
                    float zn[4];
                    #pragma unroll
                    for (int r = 0; r < 4; ++r) zn[r] = zloc[ct][r] + c * f[r];
                    uint2 p; p.x = pk2(zn[0], zn[1]); p.y = pk2(zn[2], zn[3]);
                    *(uint2*)&zb[wrbase + ct * 16] = p;
                }
                __syncthreads();
                // deferred kacc bookkeeping: overlaps next GEMM1's reads
                #pragma unroll
                for (int ct = 0; ct < 2; ++ct) {
                    const v4f f = ct ? fv1 : fv0;
                    #pragma unroll
                    for (int r = 0; r < 4; ++r) {
                        if (stage == 0) kacc[ct][r] = f[r];
                        else            kacc[ct][r] += 2.0f * f[r];
                    }
                }
            } else {
                #pragma unroll
                for (int ct = 0; ct < 2; ++ct) {
                    const v4f f = ct ? fv1 : fv0;
                    #pragma unroll
                    for (int r = 0; r < 4; ++r) {
                        kacc[ct][r] += f[r];
                        zloc[ct][r] += (h * (1.0f / 6.0f)) * kacc[ct][r];
                    }
                    uint2 p; p.x = pk2(zloc[ct][0], zloc[ct][1]);
                    p.y = pk2(zloc[ct][2], zloc[ct][3]);
                    *(uint2*)&zb[wrbase + ct * 16] = p;
                }
                __syncthreads();
            }
        }
    }

    // ---- final store (one-time, uncoalesced is fine) ----
    #pragma unroll
    for (int ct = 0; ct < 2; ++ct)
        #pragma unroll
        for (int r = 0; r < 4; ++r)
            out[(rowbase + ln) * ZDIM + wvl * 32 + ct * 16 + q * 4 + r] = zloc[ct][r];
}

extern "C" void kernel_launch(void* const* d_in, const int* in_sizes, int n_in,
                              void* d_out, int out_size, void* d_ws, size_t ws_size,
                              hipStream_t stream) {
    const float* z0 = (const float*)d_in[0];
    const float* t  = (const float*)d_in[1];
    const float* W1 = (const float*)d_in[2];
    const float* b1 = (const float*)d_in[3];
    const float* W2 = (const float*)d_in[4];
    const float* b2 = (const float*)d_in[5];
    float* out = (float*)d_out;

    dim3 grid(BS / 32);    // 32 workgroups, two 16-row tiles each
    dim3 block(1024);      // 16 waves = 2 groups of 8, 4 waves/SIMD
    hipLaunchKernelGGL(ode_mfma_kernel, grid, block, 0, stream,
                       z0, t, W1, b1, W2, b2, out);
}

// Round 14
// 5769.127 us; speedup vs baseline: 1.0000x; 1.0000x over previous
//
#include <hip/hip_runtime.h>
#include <hip/hip_bf16.h>

// NeuralODE RK4, bf16 MFMA persistent kernel, swapped-operand layout,
// DUAL-TILE 16-WAVE WG, retry with correct register budget.
// BS=1024, ZDIM=HID=256, TLEN=128 -> 127 steps x 4 stages = 508 f-evals.
//
// R13 failed on __launch_bounds__(1024,4): compiler budgeted 64 VGPR
// (8 waves/SIMD cap) -> wholesale spill (WRITE_SIZE 406MB, 5.7ms). The TLP
// hypothesis was never tested. This retry: __launch_bounds__(1024) only --
// launch feasibility forces 16 waves on 4 SIMDs = 4 waves/SIMD -> 128-reg
// cap, and the measured working set is 120 (R12). No other changes.
//
// Hypothesis (arithmetic): LDS aggregate ~112 B/cyc/CU (69TB/s ubench).
// A 16-row stage moves 128KB -> >=1170 cyc busy; observed delivery ~1536 of
// 2376 cyc/stage -> pipe saturated during GEMM phases, IDLE during ~1200cy
// of tanh/pack tails + barrier drains. A second co-resident 8-wave group
// (own tile, own buffers, shared barriers) fills those holes. Ideal
// per-32-row stage = 256KB/112B/cyc ~ 2340 cyc -> ~300us; realistic with
// sync overhead ~390-470us vs the 503us R5 anchor.
//
// Per-group schedule = exactly R5 (the proven 503us structure): hsh table,
// pre-rotated k-slices ks=(wvl+i)&7 (static reg indices; R4: runtime idx ->
// scratch), deferred kacc, split tanh tail.
//
// Swapped trick: S^T = W^T @ z^T (weights as MFMA A-operand). C/D layout:
// col(lane&15) = batch row m, row(q*4+r) = output col c. LDS round-trip is
// per-m contiguous: packed b64 writes, b128 frag reads, row stride 264 u16.

#define BS   1024
#define ZDIM 256
#define TLEN 128
#define ROWSTRIDE 264   // u16 units; 528 B = 16B-aligned, odd multiple of 4 units

typedef short v8s __attribute__((ext_vector_type(8)));
typedef float v4f __attribute__((ext_vector_type(4)));

static __device__ __forceinline__ ushort f2bf_rne(float x) {
    union { float f; unsigned u; } v; v.f = x;
    unsigned r = v.u + 0x7FFFu + ((v.u >> 16) & 1u);
    return (ushort)(r >> 16);
}

static __device__ __forceinline__ unsigned pk2(float a, float b) {
    union { __hip_bfloat162 h; unsigned u; } cv;
    cv.h = __float22bfloat162_rn(make_float2(a, b));
    return cv.u;
}

static __device__ __forceinline__ float fast_tanh(float x) {
    // tanh(x) = 1 - 2/(exp2(2x*log2e)+1); v_exp + v_rcp, no slow libm div
    float e = __builtin_amdgcn_exp2f(2.88539008177793f * x);
    float r = __builtin_amdgcn_rcpf(e + 1.0f);
    return 1.0f - 2.0f * r;
}

__global__ __launch_bounds__(1024)
void ode_mfma_kernel(const float* __restrict__ z0,
                     const float* __restrict__ t,
                     const float* __restrict__ W1,
                     const float* __restrict__ b1,
                     const float* __restrict__ W2,
                     const float* __restrict__ b2,
                     float* __restrict__ out)
{
    // per-group state buffers, swapped layout: buf[m][c] bf16
    __shared__ ushort zbuf[2][16 * ROWSTRIDE];
    __shared__ ushort hbuf[2][16 * ROWSTRIDE];
    __shared__ float  hsh[TLEN];            // per-step h = t[s+1]-t[s]

    const int tid  = threadIdx.x;
    const int wv   = tid >> 6;        // 0..15
    const int grp  = wv >> 3;         // 0: tile A (waves 0-7), 1: tile B
    const int wvl  = wv & 7;          // wave within group
    const int lane = tid & 63;
    const int q    = lane >> 4;       // 0..3
    const int ln   = lane & 15;       // = batch row m (within tile)
    const int rowbase = blockIdx.x * 32 + grp * 16;

    ushort* const zb = zbuf[grp];
    ushort* const hb = hbuf[grp];

    if (tid < TLEN - 1) hsh[tid] = t[tid + 1] - t[tid];

    // ---- one-time: weights -> registers, A-frag layout, PRE-ROTATED ----
    // wf[ct][i] holds k-slice ks=(wvl+i)&7: lane has W[k=32ks+8q+j][c=32wvl+16ct+ln]
    v8s w1f[2][8], w2f[2][8];
    #pragma unroll
    for (int ct = 0; ct < 2; ++ct) {
        const int c = wvl * 32 + ct * 16 + ln;
        #pragma unroll
        for (int i = 0; i < 8; ++i) {
            const int ks = (wvl + i) & 7;
            v8s a, b;
            #pragma unroll
            for (int j = 0; j < 8; ++j) {
                const int k = ks * 32 + q * 8 + j;
                a[j] = (short)f2bf_rne(W1[k * ZDIM + c]);
                b[j] = (short)f2bf_rne(W2[k * ZDIM + c]);
            }
            w1f[ct][i] = a;
            w2f[ct][i] = b;
        }
    }

    // biases in C'-layout: value row (c = 32wvl + 16ct + 4q + r)
    v4f b1f[2], b2f[2];
    #pragma unroll
    for (int ct = 0; ct < 2; ++ct)
        #pragma unroll
        for (int r = 0; r < 4; ++r) {
            b1f[ct][r] = b1[wvl * 32 + ct * 16 + q * 4 + r];
            b2f[ct][r] = b2[wvl * 32 + ct * 16 + q * 4 + r];
        }

    // LDS offsets (u16 units); rdaddr[i] carries the matching slice rotation
    const int rdbase = ln * ROWSTRIDE + q * 8;             // + 32*ks, b128 reads
    const int wrbase = ln * ROWSTRIDE + wvl * 32 + q * 4;  // + 16*ct,  b64 writes
    int rdaddr[8];
    #pragma unroll
    for (int i = 0; i < 8; ++i)
        rdaddr[i] = rdbase + ((wvl + i) & 7) * 32;

    // ---- initial state ----
    float zloc[2][4];   // z[m=ln][c = 32wvl+16ct+4q+r], fp32
    #pragma unroll
    for (int ct = 0; ct < 2; ++ct) {
        #pragma unroll
        for (int r = 0; r < 4; ++r)
            zloc[ct][r] = z0[(rowbase + ln) * ZDIM + wvl * 32 + ct * 16 + q * 4 + r];
        uint2 p; p.x = pk2(zloc[ct][0], zloc[ct][1]); p.y = pk2(zloc[ct][2], zloc[ct][3]);
        *(uint2*)&zb[wrbase + ct * 16] = p;
    }
    __syncthreads();

    float kacc[2][4];

    #pragma unroll 1
    for (int step = 0; step < TLEN - 1; ++step) {
        const float h = hsh[step];

        #pragma unroll
        for (int stage = 0; stage < 4; ++stage) {
            // ---- GEMM1: S^T = W1^T z^T + b1 (rotated slice order) ----
            v4f acc0 = b1f[0], acc1 = b1f[1];
            #pragma unroll
            for (int i = 0; i < 8; ++i) {
                const v8s zf = *(const v8s*)&zb[rdaddr[i]];
                acc0 = __builtin_amdgcn_mfma_f32_16x16x32_bf16(w1f[0][i], zf, acc0, 0, 0, 0);
                acc1 = __builtin_amdgcn_mfma_f32_16x16x32_bf16(w1f[1][i], zf, acc1, 0, 0, 0);
            }
            // tanh -> hbuf; write p0 before computing p1 (shorter tail)
            {
                uint2 p0;
                p0.x = pk2(fast_tanh(acc0[0]), fast_tanh(acc0[1]));
                p0.y = pk2(fast_tanh(acc0[2]), fast_tanh(acc0[3]));
                *(uint2*)&hb[wrbase] = p0;
                uint2 p1;
                p1.x = pk2(fast_tanh(acc1[0]), fast_tanh(acc1[1]));
                p1.y = pk2(fast_tanh(acc1[2]), fast_tanh(acc1[3]));
                *(uint2*)&hb[wrbase + 16] = p1;
            }
            __syncthreads();

            // ---- GEMM2: f^T = W2^T h^T + b2 (rotated slice order) ----
            v4f fv0 = b2f[0], fv1 = b2f[1];
            #pragma unroll
            for (int i = 0; i < 8; ++i) {
                const v8s hf = *(const v8s*)&hb[rdaddr[i]];
                fv0 = __builtin_amdgcn_mfma_f32_16x16x32_bf16(w2f[0][i], hf, fv0, 0, 0, 0);
                fv1 = __builtin_amdgcn_mfma_f32_16x16x32_bf16(w2f[1][i], hf, fv1, 0, 0, 0);
            }

            // ---- RK4 epilogue: only zn pack+write before the barrier ----
            if (stage < 3) {
                const float c = (stage == 2) ? h : 0.5f * h;
                #pragma unroll
                for (int ct = 0; ct < 2; ++ct) {
                    const v4f f = ct ? fv1 : fv0;
                    float zn[4];
                    #pragma unroll
                    for (int r = 0; r < 4; ++r) zn[r] = zloc[ct][r] + c * f[r];
                    uint2 p; p.x = pk2(zn[0], zn[1]); p.y = pk2(zn[2], zn[3]);
                    *(uint2*)&zb[wrbase + ct * 16] = p;
                }
                __syncthreads();
                // deferred kacc bookkeeping: overlaps next GEMM1's reads
                #pragma unroll
                for (int ct = 0; ct < 2; ++ct) {
                    const v4f f = ct ? fv1 : fv0;
                    #pragma unroll
                    for (int r = 0; r < 4; ++r) {
                        if (stage == 0) kacc[ct][r] = f[r];
                        else            kacc[ct][r] += 2.0f * f[r];
                    }
                }
            } else {
                #pragma unroll
                for (int ct = 0; ct < 2; ++ct) {
                    const v4f f = ct ? fv1 : fv0;
                    #pragma unroll
                    for (int r = 0; r < 4; ++r) {
                        kacc[ct][r] += f[r];
                        zloc[ct][r] += (h * (1.0f / 6.0f)) * kacc[ct][r];
                    }
                    uint2 p; p.x = pk2(zloc[ct][0], zloc[ct][1]);
                    p.y = pk2(zloc[ct][2], zloc[ct][3]);
                    *(uint2*)&zb[wrbase + ct * 16] = p;
                }
                __syncthreads();
            }
        }
    }

    // ---- final store (one-time, uncoalesced is fine) ----
    #pragma unroll
    for (int ct = 0; ct < 2; ++ct)
        #pragma unroll
        for (int r = 0; r < 4; ++r)
            out[(rowbase + ln) * ZDIM + wvl * 32 + ct * 16 + q * 4 + r] = zloc[ct][r];
}

extern "C" void kernel_launch(void* const* d_in, const int* in_sizes, int n_in,
                              void* d_out, int out_size, void* d_ws, size_t ws_size,
                              hipStream_t stream) {
    const float* z0 = (const float*)d_in[0];
    const float* t  = (const float*)d_in[1];
    const float* W1 = (const float*)d_in[2];
    const float* b1 = (const float*)d_in[3];
    const float* W2 = (const float*)d_in[4];
    const float* b2 = (const float*)d_in[5];
    float* out = (float*)d_out;

    dim3 grid(BS / 32);    // 32 workgroups, two 16-row tiles each
    dim3 block(1024);      // 16 waves = 2 groups of 8, 4 waves/SIMD
    hipLaunchKernelGGL(ode_mfma_kernel, grid, block, 0, stream,
                       z0, t, W1, b1, W2, b2, out);
}